// Round 11
// baseline (2658.139 us; speedup 1.0000x reference)
//
#include <hip/hip_runtime.h>
#include <hip/hip_bf16.h>

#define BB 512      // batch
#define DD 2048     // input dim
#define KK 4096     // code dim
#define CC 512      // cause dim
#define LR 0.001f
#define GAMMA 0.1f

typedef __attribute__((ext_vector_type(8))) short short8;
typedef __attribute__((ext_vector_type(4))) float f32x4;

__device__ __forceinline__ unsigned short f2bf(float f) {
  union { float f; unsigned u; } x; x.f = f;
  unsigned r = x.u + 0x7FFF + ((x.u >> 16) & 1);   // RNE
  return (unsigned short)(r >> 16);
}

__device__ __forceinline__ float bf2f(unsigned v) {
  union { unsigned u; float f; } x; x.u = v << 16; return x.f;
}

__device__ __forceinline__ f32x4 ld4bf(const unsigned short* p) {
  const uint2 q = *(const uint2*)p;
  return f32x4{bf2f(q.x & 0xffffu), bf2f(q.x >> 16),
               bf2f(q.y & 0xffffu), bf2f(q.y >> 16)};
}

__device__ __forceinline__ void g2l16(const void* g, void* l) {
  __builtin_amdgcn_global_load_lds(
      (const __attribute__((address_space(1))) void*)g,
      (__attribute__((address_space(3))) void*)l, 16, 0, 0);
}

__device__ __forceinline__ void store4bf(unsigned short* p, f32x4 v) {
  const unsigned lo = (unsigned)f2bf(v[0]) | ((unsigned)f2bf(v[1]) << 16);
  const unsigned hi = (unsigned)f2bf(v[2]) | ((unsigned)f2bf(v[3]) << 16);
  *(uint2*)p = uint2{lo, hi};
}

// ---------------------------------------------------------------------------
// R8-proven 64x64-tile K-loop, BK=64, mfma 16x16x32, 4 waves 2x2 (wave tile
// 32x32). 3 LDS buffer sets (48 KB -> 3 blocks/CU), 2 tiles staged ahead,
// stage issued right after barrier, counted vmcnt(4). XOR-swizzled LDS via
// pre-swizzled global source (rule #21). Single barrier/iter (R4-R8 proven).
// ---------------------------------------------------------------------------
__device__ __forceinline__ void mm_tile(
    const unsigned short* __restrict__ ag,
    const unsigned short* __restrict__ bg,
    int Kd, int nt,
    unsigned short* As, unsigned short* Bs,  // [3][4096] each
    int lbase, int fr, int fq, int wr, int wc,
    f32x4 acc[2][2]) {
  auto STG = [&](int ti, int buf) {
    const int k0 = ti << 6;
    unsigned short* Ab = As + buf * 4096;
    unsigned short* Bb = Bs + buf * 4096;
    g2l16(ag + k0, Ab + lbase);
    g2l16(ag + (size_t)32 * Kd + k0, Ab + 2048 + lbase);
    g2l16(bg + k0, Bb + lbase);
    g2l16(bg + (size_t)32 * Kd + k0, Bb + 2048 + lbase);
  };
#pragma unroll
  for (int p = 0; p < 2; p++)
    if (p < nt) STG(p, p);

  int cb = 0, sb = 2;
  for (int t = 0; t < nt; t++) {
    if (t + 1 < nt) asm volatile("s_waitcnt vmcnt(4)" ::: "memory");
    else            asm volatile("s_waitcnt vmcnt(0)" ::: "memory");
    __builtin_amdgcn_s_barrier();
    if (t + 2 < nt) STG(t + 2, sb);

    const unsigned short* Ab = As + cb * 4096;
    const unsigned short* Bb = Bs + cb * 4096;
#pragma unroll
    for (int kk = 0; kk < 2; kk++) {
      const int kx = (kk * 64 + fq * 16) ^ ((fr & 7) << 4);
      short8 af[2], bf2[2];
#pragma unroll
      for (int m = 0; m < 2; m++)
        af[m] = *(const short8*)((const char*)Ab + (wr * 32 + m * 16 + fr) * 128 + kx);
#pragma unroll
      for (int n = 0; n < 2; n++)
        bf2[n] = *(const short8*)((const char*)Bb + (wc * 32 + n * 16 + fr) * 128 + kx);
#pragma unroll
      for (int m = 0; m < 2; m++)
#pragma unroll
        for (int n = 0; n < 2; n++)
          acc[m][n] = __builtin_amdgcn_mfma_f32_16x16x32_bf16(af[m], bf2[n], acc[m][n], 0, 0, 0);
    }
    cb = (cb + 1 == 3) ? 0 : cb + 1;
    sb = (sb + 1 == 3) ? 0 : sb + 1;
  }
}

#define LANE_SETUP                                             \
  const int tid = threadIdx.x;                                 \
  const int w = tid >> 6, l = tid & 63;                        \
  const int wr = w >> 1, wc = w & 1;                           \
  const int fr = l & 15, fq = l >> 4;                          \
  const int srow = w * 8 + (l >> 3);                           \
  const int scol = 8 * ((l & 7) ^ (l >> 3));                   \
  const int lbase = w * 512;

#define ACC_INIT(a)                                            \
  _Pragma("unroll") for (int m = 0; m < 2; m++)                \
  _Pragma("unroll") for (int n = 0; n < 2; n++)                \
      a[m][n] = f32x4{0.f, 0.f, 0.f, 0.f};

// C/D 16x16 layout: col = lane&15, row = (lane>>4)*4 + j
#define ACC_STORE(dst, N)                                      \
  _Pragma("unroll") for (int m = 0; m < 2; m++)                \
  _Pragma("unroll") for (int n = 0; n < 2; n++)                \
  _Pragma("unroll") for (int j2 = 0; j2 < 4; j2++)             \
      (dst)[(size_t)(bm + wr * 32 + m * 16 + fq * 4 + j2) * (N)\
            + bn + wc * 32 + n * 16 + fr] = acc[m][n][j2];

#define ACC_STORE_BF(dst, N)                                   \
  _Pragma("unroll") for (int m = 0; m < 2; m++)                \
  _Pragma("unroll") for (int n = 0; n < 2; n++)                \
  _Pragma("unroll") for (int j2 = 0; j2 < 4; j2++)             \
      (dst)[(size_t)(bm + wr * 32 + m * 16 + fq * 4 + j2) * (N)\
            + bn + wc * 32 + n * 16 + fr] = f2bf(acc[m][n][j2]);

// Launch A: j<1024 -> gx partials (split-K=2, 16 iters): gxpb[ks] = r@Wb^T (bf16)
//           j>=1024 -> z tiles (8 iters): zb = ub@Vt^T (bf16)
__global__ __launch_bounds__(256, 3)
void zgxp_k(const unsigned short* __restrict__ r,    // (BB,DD)
            const unsigned short* __restrict__ Wb,   // (KK,DD)
            const unsigned short* __restrict__ ub,   // (BB,CC)
            const unsigned short* __restrict__ Vt,   // (KK,CC)
            unsigned short* __restrict__ gxpb,       // 2 x (BB,KK) bf16
            unsigned short* __restrict__ zb) {       // (BB,KK) bf16
  __shared__ unsigned short As[3][4096];
  __shared__ unsigned short Bs[3][4096];
  LANE_SETUP
  const int j = blockIdx.x;
  f32x4 acc[2][2];
  ACC_INIT(acc)
  if (j < 1024) {
    const int T = j >> 1, ks = j & 1;                // T in [0,512)
    const int bm = (T >> 6) * 64, bn = (T & 63) * 64;
    mm_tile(r  + (size_t)(bm + srow) * DD + ks * 1024 + scol,
            Wb + (size_t)(bn + srow) * DD + ks * 1024 + scol,
            DD, 16, &As[0][0], &Bs[0][0], lbase, fr, fq, wr, wc, acc);
    unsigned short* dst = gxpb + (size_t)ks * BB * KK;
    ACC_STORE_BF(dst, KK)
  } else {
    const int T = j - 1024;                          // [0,512)
    const int bm = (T >> 6) * 64, bn = (T & 63) * 64;
    mm_tile(ub + (size_t)(bm + srow) * CC + scol,
            Vt + (size_t)(bn + srow) * CC + scol,
            CC, 8, &As[0][0], &Bs[0][0], lbase, fr, fq, wr, wc, acc);
    ACC_STORE_BF(zb, KK)
  }
}

// Launch B: prox-x over BB*KK: v = gxpb0+gxpb1; x = prox(x - 2lr*v, thr(zb));
// writes x (fp32), xb, g (bf16)
__global__ __launch_bounds__(256) void ep_x_k(const unsigned short* __restrict__ gxpb,
                                              const unsigned short* __restrict__ zb,
                                              float* __restrict__ x,
                                              unsigned short* __restrict__ xb,
                                              unsigned short* __restrict__ g) {
  const int i = blockIdx.x * 256 + threadIdx.x;      // 4-elem group
  f32x4 v = ld4bf(gxpb + (size_t)i * 4);
  v += ld4bf(gxpb + (size_t)BB * KK + (size_t)i * 4);
  const f32x4 zv = ld4bf(zb + (size_t)i * 4);
  const f32x4 xo = ((const f32x4*)x)[i];
  f32x4 xn, gg;
#pragma unroll
  for (int j = 0; j < 4; j++) {
    const float e = __expf(-zv[j]);
    const float thr = (LR * GAMMA * 0.5f) * (1.0f + e);
    const float xv = xo[j] - (2.0f * LR) * v[j];
    const float t = fmaxf(xv - thr, 0.f) + fminf(xv + thr, 0.f);
    xn[j] = t;
    gg[j] = (-0.5f * GAMMA) * e * fabsf(t);
  }
  ((f32x4*)x)[i] = xn;
  store4bf(xb + (size_t)i * 4, xn);
  store4bf(g + (size_t)i * 4, gg);
}

// Launch C: j<1024 -> out partials (split-K=4, 16 iters); j>=1024 -> gu
// partials (split-K=8, 8 iters). FINAL=0: bf16 partials + per-tile counter;
// the last-arriving block re-reads all slices (fixed ks order -> determin-
// istic) and fuses the epilogue: out-tiles -> r = sum - inputs (bf16);
// gu-tiles -> u-prox (u fp32, ub bf16). Counter reset by reducer -> all
// counters are 0 at launch end (graph-replay safe). FINAL=1: out jobs only,
// fp32 partials, no counters (final out precision).
template<int FINAL>
__global__ __launch_bounds__(256, 3)
void cgo_k(const unsigned short* __restrict__ xb,   // (BB,KK)
           const unsigned short* __restrict__ Wt,   // (DD,KK)
           const unsigned short* __restrict__ g,    // (BB,KK)
           const unsigned short* __restrict__ Vb,   // (CC,KK)
           unsigned short* __restrict__ outpb,      // 4 x (BB,DD) bf16
           unsigned short* __restrict__ gupb,       // 8 x (BB,CC) bf16
           float* __restrict__ outp32,              // 4 x (BB,DD) fp32 (FINAL)
           const float* __restrict__ inputs,        // (BB,DD)
           float* __restrict__ u,                   // (BB,CC) io
           unsigned short* __restrict__ ub,         // (BB,CC)
           unsigned short* __restrict__ r,          // (BB,DD)
           unsigned* __restrict__ cnt) {            // [256 out + 64 gu]
  __shared__ unsigned short As[3][4096];
  __shared__ unsigned short Bs[3][4096];
  __shared__ int red;
  LANE_SETUP
  const int j = blockIdx.x;
  f32x4 acc[2][2];
  ACC_INIT(acc)
  if (j < 1024) {
    const int T = j >> 2, ks = j & 3;                // T in [0,256)
    const int bm = (T >> 5) * 64, bn = (T & 31) * 64;
    mm_tile(xb + (size_t)(bm + srow) * KK + ks * 1024 + scol,
            Wt + (size_t)(bn + srow) * KK + ks * 1024 + scol,
            KK, 16, &As[0][0], &Bs[0][0], lbase, fr, fq, wr, wc, acc);
    if constexpr (FINAL) {
      float* dst = outp32 + (size_t)ks * BB * DD;
      ACC_STORE(dst, DD)
    } else {
      unsigned short* dst = outpb + (size_t)ks * BB * DD;
      ACC_STORE_BF(dst, DD)
      __threadfence();                               // release my partial
      __syncthreads();                               // whole block flushed
      if (tid == 0) red = ((int)atomicAdd(&cnt[T], 1u) == 3);
      __syncthreads();
      if (red) {
        __threadfence();                             // acquire others' partials
        for (int e = tid * 4; e < 4096; e += 1024) { // 64x64 tile
          const int tr = e >> 6, tc = e & 63;
          const size_t base = (size_t)(bm + tr) * DD + bn + tc;
          f32x4 s = ld4bf(outpb + base);
          s += ld4bf(outpb + (size_t)BB * DD + base);
          s += ld4bf(outpb + (size_t)2 * BB * DD + base);
          s += ld4bf(outpb + (size_t)3 * BB * DD + base);
          s -= *(const f32x4*)(inputs + base);
          store4bf(r + base, s);
        }
        if (tid == 0)
          __hip_atomic_store(&cnt[T], 0u, __ATOMIC_RELAXED, __HIP_MEMORY_SCOPE_AGENT);
      }
    }
  } else {
    const int jj = j - 1024;                         // [0,512)
    const int T = jj >> 3, ks = jj & 7;              // T in [0,64)
    const int bm = (T >> 3) * 64, bn = (T & 7) * 64;
    mm_tile(g  + (size_t)(bm + srow) * KK + ks * 512 + scol,
            Vb + (size_t)(bn + srow) * KK + ks * 512 + scol,
            KK, 8, &As[0][0], &Bs[0][0], lbase, fr, fq, wr, wc, acc);
    unsigned short* dst = gupb + (size_t)ks * BB * CC;
    ACC_STORE_BF(dst, CC)
    __threadfence();
    __syncthreads();
    if (tid == 0) red = ((int)atomicAdd(&cnt[256 + T], 1u) == 7);
    __syncthreads();
    if (red) {
      __threadfence();
      for (int e = tid * 4; e < 4096; e += 1024) {   // 64x64 tile
        const int tr = e >> 6, tc = e & 63;
        const size_t base = (size_t)(bm + tr) * CC + bn + tc;
        f32x4 v = f32x4{0.f, 0.f, 0.f, 0.f};
#pragma unroll
        for (int k2 = 0; k2 < 8; k2++)
          v += ld4bf(gupb + (size_t)k2 * BB * CC + base);
        const f32x4 uo = *(const f32x4*)(u + base);
        f32x4 un;
#pragma unroll
        for (int q = 0; q < 4; q++) {
          const float gv = v[q] + (0.02f * GAMMA) * uo[q];
          const float uu = uo[q] - LR * gv;
          un[q] = fmaxf(uu - (LR * GAMMA), 0.f) + fminf(uu + (LR * GAMMA), 0.f);
        }
        *(f32x4*)(u + base) = un;
        store4bf(ub + base, un);
      }
      if (tid == 0)
        __hip_atomic_store(&cnt[256 + T], 0u, __ATOMIC_RELAXED, __HIP_MEMORY_SCOPE_AGENT);
    }
  }
}

// final: out = sum 4 outp32 (fp32)
__global__ __launch_bounds__(256) void ep_out_k(const float* __restrict__ outp32,
                                                float* __restrict__ out) {
  const int i = blockIdx.x * 256 + threadIdx.x;
  f32x4 s = f32x4{0.f, 0.f, 0.f, 0.f};
#pragma unroll
  for (int k = 0; k < 4; k++) s += ((const f32x4*)(outp32 + (size_t)k * BB * DD))[i];
  ((f32x4*)out)[i] = s;
}

// ---- one-time conversion / init kernels ----

__global__ __launch_bounds__(256)
void convtrans_k(const float* __restrict__ src, unsigned short* __restrict__ b,
                 unsigned short* __restrict__ t, int R, int C) {
  __shared__ float tile[64][65];
  const int tid = threadIdx.x;
  const int tr = blockIdx.y * 64;
  const int tc = blockIdx.x * 64;
  const int lr = tid >> 4;
  const int lc = (tid & 15) * 4;
#pragma unroll
  for (int i = 0; i < 4; i++) {
    const float4 v = *(const float4*)(src + (size_t)(tr + lr + 16 * i) * C + tc + lc);
    tile[lr + 16 * i][lc + 0] = v.x;
    tile[lr + 16 * i][lc + 1] = v.y;
    tile[lr + 16 * i][lc + 2] = v.z;
    tile[lr + 16 * i][lc + 3] = v.w;
    store4bf(b + (size_t)(tr + lr + 16 * i) * C + tc + lc, f32x4{v.x, v.y, v.z, v.w});
  }
  __syncthreads();
#pragma unroll
  for (int j = 0; j < 16; j++) {
    const int idx = tid + j * 256;
    const int c = idx >> 6;
    const int rr = idx & 63;
    t[(size_t)(tc + c) * R + tr + rr] = f2bf(tile[rr][c]);
  }
}

__global__ void zero_k(unsigned int* p, int n) {
  const int i = blockIdx.x * blockDim.x + threadIdx.x;
  if (i < n) p[i] = 0u;
}

__global__ void initu_k(const float* __restrict__ u0, float* __restrict__ u,
                        unsigned short* __restrict__ ub, int n) {
  const int i = blockIdx.x * blockDim.x + threadIdx.x;
  if (i < n) {
    const float v = u0[i];
    u[i] = v;
    ub[i] = f2bf(v);
  }
}

__global__ __launch_bounds__(256) void r0_k(const float* __restrict__ inputs,
                                            unsigned short* __restrict__ r) {
  const int i = blockIdx.x * 256 + threadIdx.x;
  const f32x4 v = ((const f32x4*)inputs)[i];
  store4bf(r + (size_t)i * 4, f32x4{0.f, 0.f, 0.f, 0.f} - v);
}

extern "C" void kernel_launch(void* const* d_in, const int* in_sizes, int n_in,
                              void* d_out, int out_size, void* d_ws, size_t ws_size,
                              hipStream_t stream) {
  const float* inputs = (const float*)d_in[0];   // (BB, DD)
  const float* W      = (const float*)d_in[1];   // (KK, DD)
  const float* V      = (const float*)d_in[2];   // (CC, KK)
  const float* u0     = (const float*)d_in[3];   // (BB, CC)
  float* out = (float*)d_out;                    // (BB, DD)

  char* ws = (char*)d_ws;
  size_t off = 0;
  auto alloc = [&](size_t bytes) -> void* {
    void* p = ws + off;
    off += (bytes + 255) & ~(size_t)255;
    return p;
  };
  unsigned short* Wb = (unsigned short*)alloc((size_t)KK * DD * 2);  // W  (KK,DD)
  unsigned short* Wt = (unsigned short*)alloc((size_t)DD * KK * 2);  // W^T (DD,KK)
  unsigned short* Vb = (unsigned short*)alloc((size_t)CC * KK * 2);  // V  (CC,KK)
  unsigned short* Vt = (unsigned short*)alloc((size_t)KK * CC * 2);  // V^T (KK,CC)
  unsigned short* xb = (unsigned short*)alloc((size_t)BB * KK * 2);
  unsigned short* g  = (unsigned short*)alloc((size_t)BB * KK * 2);
  unsigned short* r  = (unsigned short*)alloc((size_t)BB * DD * 2);
  unsigned short* ub = (unsigned short*)alloc((size_t)BB * CC * 2);
  float* x = (float*)alloc((size_t)BB * KK * 4);
  float* u = (float*)alloc((size_t)BB * CC * 4);
  unsigned short* gxpb  = (unsigned short*)alloc((size_t)2 * BB * KK * 2);  // 8 MB
  unsigned short* zb    = (unsigned short*)alloc((size_t)BB * KK * 2);      // 4 MB
  unsigned short* outpb = (unsigned short*)alloc((size_t)4 * BB * DD * 2);  // 8 MB
  unsigned short* gupb  = (unsigned short*)alloc((size_t)8 * BB * CC * 2);  // 4 MB
  float* outp32 = (float*)alloc((size_t)4 * BB * DD * 4);                   // 16 MB
  unsigned* cnt = (unsigned*)alloc(320 * 4);

  convtrans_k<<<dim3(DD / 64, KK / 64), 256, 0, stream>>>(W, Wb, Wt, KK, DD);
  convtrans_k<<<dim3(KK / 64, CC / 64), 256, 0, stream>>>(V, Vb, Vt, CC, KK);
  zero_k<<<(BB * KK / 2 + 255) / 256, 256, 0, stream>>>((unsigned int*)xb, BB * KK / 2);
  zero_k<<<(BB * KK + 255) / 256, 256, 0, stream>>>((unsigned int*)x, BB * KK);
  zero_k<<<2, 256, 0, stream>>>(cnt, 320);
  initu_k<<<(BB * CC + 255) / 256, 256, 0, stream>>>(u0, u, ub, BB * CC);
  r0_k<<<BB * DD / 4 / 256, 256, 0, stream>>>(inputs, r);

  for (int t = 0; t < 9; t++) {
    // A: gx-partials_t (1024 x 16 iters, bf16) + z_t (512 x 8 iters, bf16)
    zgxp_k<<<1536, 256, 0, stream>>>(r, Wb, ub, Vt, gxpb, zb);
    // B: prox-x -> x_{t+1}, xb, g_t
    ep_x_k<<<BB * KK / 4 / 256, 256, 0, stream>>>(gxpb, zb, x, xb, g);
    if (t < 8) {
      // C: out_{t+1} (1024 x 16) + gu_t (512 x 8), fused r + u-prox reducers
      cgo_k<0><<<1536, 256, 0, stream>>>(xb, Wt, g, Vb, outpb, gupb, nullptr,
                                         inputs, u, ub, r, cnt);
    } else {
      // C: out_9 partials fp32, then final sum -> d_out
      cgo_k<1><<<1024, 256, 0, stream>>>(xb, Wt, g, Vb, outpb, gupb, outp32,
                                         inputs, u, ub, r, cnt);
      ep_out_k<<<BB * DD / 4 / 256, 256, 0, stream>>>(outp32, out);
    }
  }
}

// Round 12
// 503.974 us; speedup vs baseline: 5.2744x; 5.2744x over previous
//
#include <hip/hip_runtime.h>
#include <hip/hip_bf16.h>

#define BB 512      // batch
#define DD 2048     // input dim
#define KK 4096     // code dim
#define CC 512      // cause dim
#define LR 0.001f
#define GAMMA 0.1f

typedef __attribute__((ext_vector_type(8))) short short8;
typedef __attribute__((ext_vector_type(4))) float f32x4;

__device__ __forceinline__ unsigned short f2bf(float f) {
  union { float f; unsigned u; } x; x.f = f;
  unsigned r = x.u + 0x7FFF + ((x.u >> 16) & 1);   // RNE
  return (unsigned short)(r >> 16);
}

__device__ __forceinline__ float bf2f(unsigned v) {
  union { unsigned u; float f; } x; x.u = v << 16; return x.f;
}

__device__ __forceinline__ f32x4 ld4bf(const unsigned short* p) {
  const uint2 q = *(const uint2*)p;
  return f32x4{bf2f(q.x & 0xffffu), bf2f(q.x >> 16),
               bf2f(q.y & 0xffffu), bf2f(q.y >> 16)};
}

__device__ __forceinline__ void g2l16(const void* g, void* l) {
  __builtin_amdgcn_global_load_lds(
      (const __attribute__((address_space(1))) void*)g,
      (__attribute__((address_space(3))) void*)l, 16, 0, 0);
}

__device__ __forceinline__ void store4bf(unsigned short* p, f32x4 v) {
  const unsigned lo = (unsigned)f2bf(v[0]) | ((unsigned)f2bf(v[1]) << 16);
  const unsigned hi = (unsigned)f2bf(v[2]) | ((unsigned)f2bf(v[3]) << 16);
  *(uint2*)p = uint2{lo, hi};
}

// ---------------------------------------------------------------------------
// R8-proven 64x64-tile K-loop, BK=64, mfma 16x16x32, 4 waves 2x2 (wave tile
// 32x32). 3 LDS buffer sets (48 KB -> 3 blocks/CU), 2 tiles staged ahead,
// stage issued right after barrier, counted vmcnt(4). XOR-swizzled LDS via
// pre-swizzled global source (rule #21). Single barrier/iter (R4-R8 proven).
// ---------------------------------------------------------------------------
__device__ __forceinline__ void mm_tile(
    const unsigned short* __restrict__ ag,
    const unsigned short* __restrict__ bg,
    int Kd, int nt,
    unsigned short* As, unsigned short* Bs,  // [3][4096] each
    int lbase, int fr, int fq, int wr, int wc,
    f32x4 acc[2][2]) {
  auto STG = [&](int ti, int buf) {
    const int k0 = ti << 6;
    unsigned short* Ab = As + buf * 4096;
    unsigned short* Bb = Bs + buf * 4096;
    g2l16(ag + k0, Ab + lbase);
    g2l16(ag + (size_t)32 * Kd + k0, Ab + 2048 + lbase);
    g2l16(bg + k0, Bb + lbase);
    g2l16(bg + (size_t)32 * Kd + k0, Bb + 2048 + lbase);
  };
#pragma unroll
  for (int p = 0; p < 2; p++)
    if (p < nt) STG(p, p);

  int cb = 0, sb = 2;
  for (int t = 0; t < nt; t++) {
    if (t + 1 < nt) asm volatile("s_waitcnt vmcnt(4)" ::: "memory");
    else            asm volatile("s_waitcnt vmcnt(0)" ::: "memory");
    __builtin_amdgcn_s_barrier();
    if (t + 2 < nt) STG(t + 2, sb);

    const unsigned short* Ab = As + cb * 4096;
    const unsigned short* Bb = Bs + cb * 4096;
#pragma unroll
    for (int kk = 0; kk < 2; kk++) {
      const int kx = (kk * 64 + fq * 16) ^ ((fr & 7) << 4);
      short8 af[2], bf2[2];
#pragma unroll
      for (int m = 0; m < 2; m++)
        af[m] = *(const short8*)((const char*)Ab + (wr * 32 + m * 16 + fr) * 128 + kx);
#pragma unroll
      for (int n = 0; n < 2; n++)
        bf2[n] = *(const short8*)((const char*)Bb + (wc * 32 + n * 16 + fr) * 128 + kx);
#pragma unroll
      for (int m = 0; m < 2; m++)
#pragma unroll
        for (int n = 0; n < 2; n++)
          acc[m][n] = __builtin_amdgcn_mfma_f32_16x16x32_bf16(af[m], bf2[n], acc[m][n], 0, 0, 0);
    }
    cb = (cb + 1 == 3) ? 0 : cb + 1;
    sb = (sb + 1 == 3) ? 0 : sb + 1;
  }
}

#define LANE_SETUP                                             \
  const int tid = threadIdx.x;                                 \
  const int w = tid >> 6, l = tid & 63;                        \
  const int wr = w >> 1, wc = w & 1;                           \
  const int fr = l & 15, fq = l >> 4;                          \
  const int srow = w * 8 + (l >> 3);                           \
  const int scol = 8 * ((l & 7) ^ (l >> 3));                   \
  const int lbase = w * 512;

#define ACC_INIT(a)                                            \
  _Pragma("unroll") for (int m = 0; m < 2; m++)                \
  _Pragma("unroll") for (int n = 0; n < 2; n++)                \
      a[m][n] = f32x4{0.f, 0.f, 0.f, 0.f};

// C/D 16x16 layout: col = lane&15, row = (lane>>4)*4 + j
#define ACC_STORE(dst, N)                                      \
  _Pragma("unroll") for (int m = 0; m < 2; m++)                \
  _Pragma("unroll") for (int n = 0; n < 2; n++)                \
  _Pragma("unroll") for (int j2 = 0; j2 < 4; j2++)             \
      (dst)[(size_t)(bm + wr * 32 + m * 16 + fq * 4 + j2) * (N)\
            + bn + wc * 32 + n * 16 + fr] = acc[m][n][j2];

#define ACC_STORE_BF(dst, N)                                   \
  _Pragma("unroll") for (int m = 0; m < 2; m++)                \
  _Pragma("unroll") for (int n = 0; n < 2; n++)                \
  _Pragma("unroll") for (int j2 = 0; j2 < 4; j2++)             \
      (dst)[(size_t)(bm + wr * 32 + m * 16 + fq * 4 + j2) * (N)\
            + bn + wc * 32 + n * 16 + fr] = f2bf(acc[m][n][j2]);

// Launch A: j<1024 -> gx partials (split-K=2, 16 iters): gxpb[ks] = r@Wb^T (bf16)
//           j>=1024 -> z tiles (8 iters): zb = ub@Vt^T (bf16)
__global__ __launch_bounds__(256, 3)
void zgxp_k(const unsigned short* __restrict__ r,    // (BB,DD)
            const unsigned short* __restrict__ Wb,   // (KK,DD)
            const unsigned short* __restrict__ ub,   // (BB,CC)
            const unsigned short* __restrict__ Vt,   // (KK,CC)
            unsigned short* __restrict__ gxpb,       // 2 x (BB,KK) bf16
            unsigned short* __restrict__ zb) {       // (BB,KK) bf16
  __shared__ unsigned short As[3][4096];
  __shared__ unsigned short Bs[3][4096];
  LANE_SETUP
  const int j = blockIdx.x;
  f32x4 acc[2][2];
  ACC_INIT(acc)
  if (j < 1024) {
    const int T = j >> 1, ks = j & 1;                // T in [0,512)
    const int bm = (T >> 6) * 64, bn = (T & 63) * 64;
    mm_tile(r  + (size_t)(bm + srow) * DD + ks * 1024 + scol,
            Wb + (size_t)(bn + srow) * DD + ks * 1024 + scol,
            DD, 16, &As[0][0], &Bs[0][0], lbase, fr, fq, wr, wc, acc);
    unsigned short* dst = gxpb + (size_t)ks * BB * KK;
    ACC_STORE_BF(dst, KK)
  } else {
    const int T = j - 1024;                          // [0,512)
    const int bm = (T >> 6) * 64, bn = (T & 63) * 64;
    mm_tile(ub + (size_t)(bm + srow) * CC + scol,
            Vt + (size_t)(bn + srow) * CC + scol,
            CC, 8, &As[0][0], &Bs[0][0], lbase, fr, fq, wr, wc, acc);
    ACC_STORE_BF(zb, KK)
  }
}

// Launch C: j<1024 -> out partials (split-K=4, 16 iters): outpb[ks] = xb@Wt^T
//           j>=1024 -> gu partials (split-K=8, 8 iters):  gupb[ks] = g@Vb^T
// FINAL=1: out jobs only, fp32 partials (final output precision).
template<int FINAL>
__global__ __launch_bounds__(256, 3)
void cgo_k(const unsigned short* __restrict__ xb,   // (BB,KK)
           const unsigned short* __restrict__ Wt,   // (DD,KK)
           const unsigned short* __restrict__ g,    // (BB,KK)
           const unsigned short* __restrict__ Vb,   // (CC,KK)
           unsigned short* __restrict__ outpb,      // 4 x (BB,DD) bf16
           unsigned short* __restrict__ gupb,       // 8 x (BB,CC) bf16
           float* __restrict__ outp32) {            // 4 x (BB,DD) fp32 (FINAL)
  __shared__ unsigned short As[3][4096];
  __shared__ unsigned short Bs[3][4096];
  LANE_SETUP
  const int j = blockIdx.x;
  f32x4 acc[2][2];
  ACC_INIT(acc)
  if (j < 1024) {
    const int T = j >> 2, ks = j & 3;                // T in [0,256)
    const int bm = (T >> 5) * 64, bn = (T & 31) * 64;
    mm_tile(xb + (size_t)(bm + srow) * KK + ks * 1024 + scol,
            Wt + (size_t)(bn + srow) * KK + ks * 1024 + scol,
            KK, 16, &As[0][0], &Bs[0][0], lbase, fr, fq, wr, wc, acc);
    if constexpr (FINAL) {
      float* dst = outp32 + (size_t)ks * BB * DD;
      ACC_STORE(dst, DD)
    } else {
      unsigned short* dst = outpb + (size_t)ks * BB * DD;
      ACC_STORE_BF(dst, DD)
    }
  } else {
    const int jj = j - 1024;                         // [0,512)
    const int T = jj >> 3, ks = jj & 7;              // T in [0,64)
    const int bm = (T >> 3) * 64, bn = (T & 7) * 64;
    mm_tile(g  + (size_t)(bm + srow) * KK + ks * 512 + scol,
            Vb + (size_t)(bn + srow) * KK + ks * 512 + scol,
            KK, 8, &As[0][0], &Bs[0][0], lbase, fr, fq, wr, wc, acc);
    unsigned short* dst = gupb + (size_t)ks * BB * CC;
    ACC_STORE_BF(dst, CC)
  }
}

// Launch B: prox-x over BB*KK: v = gxpb0+gxpb1; x = prox(x - 2lr*v, thr(zb));
// writes x (fp32), xb, g (bf16)
__global__ __launch_bounds__(256) void ep_x_k(const unsigned short* __restrict__ gxpb,
                                              const unsigned short* __restrict__ zb,
                                              float* __restrict__ x,
                                              unsigned short* __restrict__ xb,
                                              unsigned short* __restrict__ g) {
  const int i = blockIdx.x * 256 + threadIdx.x;      // 4-elem group
  f32x4 v = ld4bf(gxpb + (size_t)i * 4);
  v += ld4bf(gxpb + (size_t)BB * KK + (size_t)i * 4);
  const f32x4 zv = ld4bf(zb + (size_t)i * 4);
  const f32x4 xo = ((const f32x4*)x)[i];
  f32x4 xn, gg;
#pragma unroll
  for (int j = 0; j < 4; j++) {
    const float e = __expf(-zv[j]);
    const float thr = (LR * GAMMA * 0.5f) * (1.0f + e);
    const float xv = xo[j] - (2.0f * LR) * v[j];
    const float t = fmaxf(xv - thr, 0.f) + fminf(xv + thr, 0.f);
    xn[j] = t;
    gg[j] = (-0.5f * GAMMA) * e * fabsf(t);
  }
  ((f32x4*)x)[i] = xn;
  store4bf(xb + (size_t)i * 4, xn);
  store4bf(g + (size_t)i * 4, gg);
}

// Launch D: j<256  -> u-update (sum 8 gupb + prox -> u, ub)   [256 blocks]
//           j>=256 -> r = bf16(sum 4 outpb - inputs)          [1024 blocks]
__global__ __launch_bounds__(256) void ud_k(const unsigned short* __restrict__ gupb,
                                            const unsigned short* __restrict__ outpb,
                                            const float* __restrict__ inputs,
                                            float* __restrict__ u,
                                            unsigned short* __restrict__ ub,
                                            unsigned short* __restrict__ r) {
  const int j = blockIdx.x;
  if (j < 256) {
    const int i = j * 256 + threadIdx.x;
    f32x4 v = f32x4{0.f, 0.f, 0.f, 0.f};
#pragma unroll
    for (int k = 0; k < 8; k++) v += ld4bf(gupb + (size_t)k * BB * CC + (size_t)i * 4);
    const f32x4 uo = ((const f32x4*)u)[i];
    f32x4 un;
#pragma unroll
    for (int jj = 0; jj < 4; jj++) {
      const float gv = v[jj] + (0.02f * GAMMA) * uo[jj];
      const float uu = uo[jj] - LR * gv;
      un[jj] = fmaxf(uu - (LR * GAMMA), 0.f) + fminf(uu + (LR * GAMMA), 0.f);
    }
    ((f32x4*)u)[i] = un;
    store4bf(ub + (size_t)i * 4, un);
  } else {
    const int i = (j - 256) * 256 + threadIdx.x;     // 1024 blocks
    f32x4 s = ld4bf(outpb + (size_t)i * 4);
#pragma unroll
    for (int k = 1; k < 4; k++) s += ld4bf(outpb + (size_t)k * BB * DD + (size_t)i * 4);
    s -= ((const f32x4*)inputs)[i];
    store4bf(r + (size_t)i * 4, s);
  }
}

// final: out = sum 4 outp32 (fp32)
__global__ __launch_bounds__(256) void ep_out_k(const float* __restrict__ outp32,
                                                float* __restrict__ out) {
  const int i = blockIdx.x * 256 + threadIdx.x;
  f32x4 s = f32x4{0.f, 0.f, 0.f, 0.f};
#pragma unroll
  for (int k = 0; k < 4; k++) s += ((const f32x4*)(outp32 + (size_t)k * BB * DD))[i];
  ((f32x4*)out)[i] = s;
}

// ---- one-time conversion / init kernels ----

__global__ __launch_bounds__(256)
void convtrans_k(const float* __restrict__ src, unsigned short* __restrict__ b,
                 unsigned short* __restrict__ t, int R, int C) {
  __shared__ float tile[64][65];
  const int tid = threadIdx.x;
  const int tr = blockIdx.y * 64;
  const int tc = blockIdx.x * 64;
  const int lr = tid >> 4;
  const int lc = (tid & 15) * 4;
#pragma unroll
  for (int i = 0; i < 4; i++) {
    const float4 v = *(const float4*)(src + (size_t)(tr + lr + 16 * i) * C + tc + lc);
    tile[lr + 16 * i][lc + 0] = v.x;
    tile[lr + 16 * i][lc + 1] = v.y;
    tile[lr + 16 * i][lc + 2] = v.z;
    tile[lr + 16 * i][lc + 3] = v.w;
    store4bf(b + (size_t)(tr + lr + 16 * i) * C + tc + lc, f32x4{v.x, v.y, v.z, v.w});
  }
  __syncthreads();
#pragma unroll
  for (int j = 0; j < 16; j++) {
    const int idx = tid + j * 256;
    const int c = idx >> 6;
    const int rr = idx & 63;
    t[(size_t)(tc + c) * R + tr + rr] = f2bf(tile[rr][c]);
  }
}

__global__ void zero_k(unsigned int* p, int n) {
  const int i = blockIdx.x * blockDim.x + threadIdx.x;
  if (i < n) p[i] = 0u;
}

__global__ void initu_k(const float* __restrict__ u0, float* __restrict__ u,
                        unsigned short* __restrict__ ub, int n) {
  const int i = blockIdx.x * blockDim.x + threadIdx.x;
  if (i < n) {
    const float v = u0[i];
    u[i] = v;
    ub[i] = f2bf(v);
  }
}

__global__ __launch_bounds__(256) void r0_k(const float* __restrict__ inputs,
                                            unsigned short* __restrict__ r) {
  const int i = blockIdx.x * 256 + threadIdx.x;
  const f32x4 v = ((const f32x4*)inputs)[i];
  store4bf(r + (size_t)i * 4, f32x4{0.f, 0.f, 0.f, 0.f} - v);
}

extern "C" void kernel_launch(void* const* d_in, const int* in_sizes, int n_in,
                              void* d_out, int out_size, void* d_ws, size_t ws_size,
                              hipStream_t stream) {
  const float* inputs = (const float*)d_in[0];   // (BB, DD)
  const float* W      = (const float*)d_in[1];   // (KK, DD)
  const float* V      = (const float*)d_in[2];   // (CC, KK)
  const float* u0     = (const float*)d_in[3];   // (BB, CC)
  float* out = (float*)d_out;                    // (BB, DD)

  char* ws = (char*)d_ws;
  size_t off = 0;
  auto alloc = [&](size_t bytes) -> void* {
    void* p = ws + off;
    off += (bytes + 255) & ~(size_t)255;
    return p;
  };
  unsigned short* Wb = (unsigned short*)alloc((size_t)KK * DD * 2);  // W  (KK,DD)
  unsigned short* Wt = (unsigned short*)alloc((size_t)DD * KK * 2);  // W^T (DD,KK)
  unsigned short* Vb = (unsigned short*)alloc((size_t)CC * KK * 2);  // V  (CC,KK)
  unsigned short* Vt = (unsigned short*)alloc((size_t)KK * CC * 2);  // V^T (KK,CC)
  unsigned short* xb = (unsigned short*)alloc((size_t)BB * KK * 2);
  unsigned short* g  = (unsigned short*)alloc((size_t)BB * KK * 2);
  unsigned short* r  = (unsigned short*)alloc((size_t)BB * DD * 2);
  unsigned short* ub = (unsigned short*)alloc((size_t)BB * CC * 2);
  float* x = (float*)alloc((size_t)BB * KK * 4);
  float* u = (float*)alloc((size_t)BB * CC * 4);
  unsigned short* gxpb  = (unsigned short*)alloc((size_t)2 * BB * KK * 2);  // 8 MB
  unsigned short* zb    = (unsigned short*)alloc((size_t)BB * KK * 2);      // 4 MB
  unsigned short* outpb = (unsigned short*)alloc((size_t)4 * BB * DD * 2);  // 8 MB
  unsigned short* gupb  = (unsigned short*)alloc((size_t)8 * BB * CC * 2);  // 4 MB
  float* outp32 = (float*)alloc((size_t)4 * BB * DD * 4);                   // 16 MB

  convtrans_k<<<dim3(DD / 64, KK / 64), 256, 0, stream>>>(W, Wb, Wt, KK, DD);
  convtrans_k<<<dim3(KK / 64, CC / 64), 256, 0, stream>>>(V, Vb, Vt, CC, KK);
  zero_k<<<(BB * KK / 2 + 255) / 256, 256, 0, stream>>>((unsigned int*)xb, BB * KK / 2);
  zero_k<<<(BB * KK + 255) / 256, 256, 0, stream>>>((unsigned int*)x, BB * KK);
  initu_k<<<(BB * CC + 255) / 256, 256, 0, stream>>>(u0, u, ub, BB * CC);
  r0_k<<<BB * DD / 4 / 256, 256, 0, stream>>>(inputs, r);

  for (int t = 0; t < 9; t++) {
    // A: gx-partials_t (1024 x 16 iters, bf16) + z_t (512 x 8 iters, bf16)
    zgxp_k<<<1536, 256, 0, stream>>>(r, Wb, ub, Vt, gxpb, zb);
    // B: prox-x -> x_{t+1}, xb, g_t
    ep_x_k<<<BB * KK / 4 / 256, 256, 0, stream>>>(gxpb, zb, x, xb, g);
    if (t < 8) {
      // C: out_{t+1} (1024 x 16, bf16) + gu_t (512 x 8, bf16)
      cgo_k<0><<<1536, 256, 0, stream>>>(xb, Wt, g, Vb, outpb, gupb, nullptr);
      // D: u-prox_t (256 blocks) + r_{t+1} (1024 blocks)
      ud_k<<<1280, 256, 0, stream>>>(gupb, outpb, inputs, u, ub, r);
    } else {
      // C: out_9 partials fp32, then final sum -> d_out
      cgo_k<1><<<1024, 256, 0, stream>>>(xb, Wt, g, Vb, outpb, gupb, outp32);
      ep_out_k<<<BB * DD / 4 / 256, 256, 0, stream>>>(outp32, out);
    }
  }
}

// Round 13
// 470.824 us; speedup vs baseline: 5.6457x; 1.0704x over previous
//
#include <hip/hip_runtime.h>
#include <hip/hip_bf16.h>

#define BB 512      // batch
#define DD 2048     // input dim
#define KK 4096     // code dim
#define CC 512      // cause dim
#define LR 0.001f
#define GAMMA 0.1f

typedef __attribute__((ext_vector_type(8))) short short8;
typedef __attribute__((ext_vector_type(4))) float f32x4;

__device__ __forceinline__ unsigned short f2bf(float f) {
  union { float f; unsigned u; } x; x.f = f;
  unsigned r = x.u + 0x7FFF + ((x.u >> 16) & 1);   // RNE
  return (unsigned short)(r >> 16);
}

__device__ __forceinline__ float bf2f(unsigned v) {
  union { unsigned u; float f; } x; x.u = v << 16; return x.f;
}

__device__ __forceinline__ f32x4 ld4bf(const unsigned short* p) {
  const uint2 q = *(const uint2*)p;
  return f32x4{bf2f(q.x & 0xffffu), bf2f(q.x >> 16),
               bf2f(q.y & 0xffffu), bf2f(q.y >> 16)};
}

__device__ __forceinline__ void g2l16(const void* g, void* l) {
  __builtin_amdgcn_global_load_lds(
      (const __attribute__((address_space(1))) void*)g,
      (__attribute__((address_space(3))) void*)l, 16, 0, 0);
}

__device__ __forceinline__ void store4bf(unsigned short* p, f32x4 v) {
  const unsigned lo = (unsigned)f2bf(v[0]) | ((unsigned)f2bf(v[1]) << 16);
  const unsigned hi = (unsigned)f2bf(v[2]) | ((unsigned)f2bf(v[3]) << 16);
  *(uint2*)p = uint2{lo, hi};
}

// ---------------------------------------------------------------------------
// 128x128-tile K-loop, BK=64, mfma 16x16x32, 4 waves 2x2 (wave tile 64x64,
// acc 4x4: 32 MFMA + 16 ds_read_b128 per wave-iter -> 0.5 KB LDS-read/MFMA,
// 2x the arithmetic intensity of the 64x64-tile R8 core). 2 LDS buffer sets
// (64 KB -> 2 blocks/CU). T3 minimum-2-phase schedule: stage(t+1) issued
// right after barrier, overlapping compute(t); wait-own-vmcnt(0) BEFORE the
// barrier guarantees all waves' stage(t) landed. Staging: R8's proven lane
// map (8 rows x 128B per instr, 4 calls per matrix) + XOR swizzle via
// pre-swizzled global source (rule #21).
// ---------------------------------------------------------------------------
__device__ __forceinline__ void mm128(
    const unsigned short* __restrict__ ag,   // lane-adjusted A base
    const unsigned short* __restrict__ bg,   // lane-adjusted B base
    int Kd, int nt,
    unsigned short* As, unsigned short* Bs,  // [2][8192] each
    int lbase, int fr, int fq, int wr, int wc,
    f32x4 acc[4][4]) {
  auto STG = [&](int ti, int buf) {
    const int k0 = ti << 6;
    unsigned short* Ab = As + buf * 8192;
    unsigned short* Bb = Bs + buf * 8192;
#pragma unroll
    for (int c = 0; c < 4; c++) {
      g2l16(ag + (size_t)c * 32 * Kd + k0, Ab + c * 2048 + lbase);
      g2l16(bg + (size_t)c * 32 * Kd + k0, Bb + c * 2048 + lbase);
    }
  };
  STG(0, 0);
  for (int t = 0; t < nt; t++) {
    asm volatile("s_waitcnt vmcnt(0)" ::: "memory");   // my stage(t) done
    __builtin_amdgcn_s_barrier();                      // everyone's stage(t) done,
                                                       // buf (t+1)&1 consumed
    if (t + 1 < nt) STG(t + 1, (t + 1) & 1);           // overlaps compute(t)

    const unsigned short* Ab = As + (t & 1) * 8192;
    const unsigned short* Bb = Bs + (t & 1) * 8192;
#pragma unroll
    for (int kk = 0; kk < 2; kk++) {
      const int kx = (kk * 64 + fq * 16) ^ ((fr & 7) << 4);
      short8 af[4], bf2[4];
#pragma unroll
      for (int m = 0; m < 4; m++)
        af[m] = *(const short8*)((const char*)Ab + (wr * 64 + m * 16 + fr) * 128 + kx);
#pragma unroll
      for (int n = 0; n < 4; n++)
        bf2[n] = *(const short8*)((const char*)Bb + (wc * 64 + n * 16 + fr) * 128 + kx);
#pragma unroll
      for (int m = 0; m < 4; m++)
#pragma unroll
        for (int n = 0; n < 4; n++)
          acc[m][n] = __builtin_amdgcn_mfma_f32_16x16x32_bf16(af[m], bf2[n], acc[m][n], 0, 0, 0);
    }
  }
}

#define LANE_SETUP                                             \
  const int tid = threadIdx.x;                                 \
  const int w = tid >> 6, l = tid & 63;                        \
  const int wr = w >> 1, wc = w & 1;                           \
  const int fr = l & 15, fq = l >> 4;                          \
  const int srow = w * 8 + (l >> 3);                           \
  const int scol = 8 * ((l & 7) ^ (l >> 3));                   \
  const int lbase = w * 512;

#define ACC_INIT(a)                                            \
  _Pragma("unroll") for (int m = 0; m < 4; m++)                \
  _Pragma("unroll") for (int n = 0; n < 4; n++)                \
      a[m][n] = f32x4{0.f, 0.f, 0.f, 0.f};

// C/D 16x16 layout: col = lane&15, row = (lane>>4)*4 + j
#define ACC_STORE(dst, N)                                      \
  _Pragma("unroll") for (int m = 0; m < 4; m++)                \
  _Pragma("unroll") for (int n = 0; n < 4; n++)                \
  _Pragma("unroll") for (int j2 = 0; j2 < 4; j2++)             \
      (dst)[(size_t)(bm + wr * 64 + m * 16 + fq * 4 + j2) * (N)\
            + bn + wc * 64 + n * 16 + fr] = acc[m][n][j2];

#define ACC_STORE_BF(dst, N)                                   \
  _Pragma("unroll") for (int m = 0; m < 4; m++)                \
  _Pragma("unroll") for (int n = 0; n < 4; n++)                \
  _Pragma("unroll") for (int j2 = 0; j2 < 4; j2++)             \
      (dst)[(size_t)(bm + wr * 64 + m * 16 + fq * 4 + j2) * (N)\
            + bn + wc * 64 + n * 16 + fr] = f2bf(acc[m][n][j2]);

// Launch A: j<256  -> gx partials (split-K=2, 16 iters): gxpb[ks] = r@Wb^T (bf16)
//           j>=256 -> z tiles (8 iters): zb = ub@Vt^T (bf16)
__global__ __launch_bounds__(256, 2)
void zgxp_k(const unsigned short* __restrict__ r,    // (BB,DD)
            const unsigned short* __restrict__ Wb,   // (KK,DD)
            const unsigned short* __restrict__ ub,   // (BB,CC)
            const unsigned short* __restrict__ Vt,   // (KK,CC)
            unsigned short* __restrict__ gxpb,       // 2 x (BB,KK) bf16
            unsigned short* __restrict__ zb) {       // (BB,KK) bf16
  __shared__ unsigned short As[2][8192];
  __shared__ unsigned short Bs[2][8192];
  LANE_SETUP
  const int j = blockIdx.x;
  f32x4 acc[4][4];
  ACC_INIT(acc)
  if (j < 256) {
    const int T = j >> 1, ks = j & 1;                // T in [0,128): 4 M x 32 N
    const int bm = (T >> 5) * 128, bn = (T & 31) * 128;
    mm128(r  + (size_t)(bm + srow) * DD + ks * 1024 + scol,
          Wb + (size_t)(bn + srow) * DD + ks * 1024 + scol,
          DD, 16, &As[0][0], &Bs[0][0], lbase, fr, fq, wr, wc, acc);
    unsigned short* dst = gxpb + (size_t)ks * BB * KK;
    ACC_STORE_BF(dst, KK)
  } else {
    const int T = j - 256;                           // [0,128)
    const int bm = (T >> 5) * 128, bn = (T & 31) * 128;
    mm128(ub + (size_t)(bm + srow) * CC + scol,
          Vt + (size_t)(bn + srow) * CC + scol,
          CC, 8, &As[0][0], &Bs[0][0], lbase, fr, fq, wr, wc, acc);
    ACC_STORE_BF(zb, KK)
  }
}

// Launch C: j<256  -> out partials (split-K=4, 16 iters): outpb[ks] = xb@Wt^T
//           j>=256 -> gu partials (split-K=8, 8 iters):   gupb[ks] = g@Vb^T
// FINAL=1: out jobs only, fp32 partials (final output precision).
template<int FINAL>
__global__ __launch_bounds__(256, 2)
void cgo_k(const unsigned short* __restrict__ xb,   // (BB,KK)
           const unsigned short* __restrict__ Wt,   // (DD,KK)
           const unsigned short* __restrict__ g,    // (BB,KK)
           const unsigned short* __restrict__ Vb,   // (CC,KK)
           unsigned short* __restrict__ outpb,      // 4 x (BB,DD) bf16
           unsigned short* __restrict__ gupb,       // 8 x (BB,CC) bf16
           float* __restrict__ outp32) {            // 4 x (BB,DD) fp32 (FINAL)
  __shared__ unsigned short As[2][8192];
  __shared__ unsigned short Bs[2][8192];
  LANE_SETUP
  const int j = blockIdx.x;
  f32x4 acc[4][4];
  ACC_INIT(acc)
  if (j < 256) {
    const int T = j >> 2, ks = j & 3;                // T in [0,64): 4 M x 16 N
    const int bm = (T >> 4) * 128, bn = (T & 15) * 128;
    mm128(xb + (size_t)(bm + srow) * KK + ks * 1024 + scol,
          Wt + (size_t)(bn + srow) * KK + ks * 1024 + scol,
          KK, 16, &As[0][0], &Bs[0][0], lbase, fr, fq, wr, wc, acc);
    if constexpr (FINAL) {
      float* dst = outp32 + (size_t)ks * BB * DD;
      ACC_STORE(dst, DD)
    } else {
      unsigned short* dst = outpb + (size_t)ks * BB * DD;
      ACC_STORE_BF(dst, DD)
    }
  } else {
    const int jj = j - 256;                          // [0,128)
    const int T = jj >> 3, ks = jj & 7;              // T in [0,16): 4 M x 4 N
    const int bm = (T >> 2) * 128, bn = (T & 3) * 128;
    mm128(g  + (size_t)(bm + srow) * KK + ks * 512 + scol,
          Vb + (size_t)(bn + srow) * KK + ks * 512 + scol,
          KK, 8, &As[0][0], &Bs[0][0], lbase, fr, fq, wr, wc, acc);
    unsigned short* dst = gupb + (size_t)ks * BB * CC;
    ACC_STORE_BF(dst, CC)
  }
}

// Launch B: prox-x over BB*KK: v = gxpb0+gxpb1; x = prox(x - 2lr*v, thr(zb));
// writes x (fp32), xb, g (bf16)
__global__ __launch_bounds__(256) void ep_x_k(const unsigned short* __restrict__ gxpb,
                                              const unsigned short* __restrict__ zb,
                                              float* __restrict__ x,
                                              unsigned short* __restrict__ xb,
                                              unsigned short* __restrict__ g) {
  const int i = blockIdx.x * 256 + threadIdx.x;      // 4-elem group
  f32x4 v = ld4bf(gxpb + (size_t)i * 4);
  v += ld4bf(gxpb + (size_t)BB * KK + (size_t)i * 4);
  const f32x4 zv = ld4bf(zb + (size_t)i * 4);
  const f32x4 xo = ((const f32x4*)x)[i];
  f32x4 xn, gg;
#pragma unroll
  for (int j = 0; j < 4; j++) {
    const float e = __expf(-zv[j]);
    const float thr = (LR * GAMMA * 0.5f) * (1.0f + e);
    const float xv = xo[j] - (2.0f * LR) * v[j];
    const float t = fmaxf(xv - thr, 0.f) + fminf(xv + thr, 0.f);
    xn[j] = t;
    gg[j] = (-0.5f * GAMMA) * e * fabsf(t);
  }
  ((f32x4*)x)[i] = xn;
  store4bf(xb + (size_t)i * 4, xn);
  store4bf(g + (size_t)i * 4, gg);
}

// Launch D: j<256  -> u-update (sum 8 gupb + prox -> u, ub)   [256 blocks]
//           j>=256 -> r = bf16(sum 4 outpb - inputs)          [1024 blocks]
__global__ __launch_bounds__(256) void ud_k(const unsigned short* __restrict__ gupb,
                                            const unsigned short* __restrict__ outpb,
                                            const float* __restrict__ inputs,
                                            float* __restrict__ u,
                                            unsigned short* __restrict__ ub,
                                            unsigned short* __restrict__ r) {
  const int j = blockIdx.x;
  if (j < 256) {
    const int i = j * 256 + threadIdx.x;
    f32x4 v = f32x4{0.f, 0.f, 0.f, 0.f};
#pragma unroll
    for (int k = 0; k < 8; k++) v += ld4bf(gupb + (size_t)k * BB * CC + (size_t)i * 4);
    const f32x4 uo = ((const f32x4*)u)[i];
    f32x4 un;
#pragma unroll
    for (int jj = 0; jj < 4; jj++) {
      const float gv = v[jj] + (0.02f * GAMMA) * uo[jj];
      const float uu = uo[jj] - LR * gv;
      un[jj] = fmaxf(uu - (LR * GAMMA), 0.f) + fminf(uu + (LR * GAMMA), 0.f);
    }
    ((f32x4*)u)[i] = un;
    store4bf(ub + (size_t)i * 4, un);
  } else {
    const int i = (j - 256) * 256 + threadIdx.x;     // 1024 blocks
    f32x4 s = ld4bf(outpb + (size_t)i * 4);
#pragma unroll
    for (int k = 1; k < 4; k++) s += ld4bf(outpb + (size_t)k * BB * DD + (size_t)i * 4);
    s -= ((const f32x4*)inputs)[i];
    store4bf(r + (size_t)i * 4, s);
  }
}

// final: out = sum 4 outp32 (fp32)
__global__ __launch_bounds__(256) void ep_out_k(const float* __restrict__ outp32,
                                                float* __restrict__ out) {
  const int i = blockIdx.x * 256 + threadIdx.x;
  f32x4 s = f32x4{0.f, 0.f, 0.f, 0.f};
#pragma unroll
  for (int k = 0; k < 4; k++) s += ((const f32x4*)(outp32 + (size_t)k * BB * DD))[i];
  ((f32x4*)out)[i] = s;
}

// ---- one-time conversion / init kernels ----

__global__ __launch_bounds__(256)
void convtrans_k(const float* __restrict__ src, unsigned short* __restrict__ b,
                 unsigned short* __restrict__ t, int R, int C) {
  __shared__ float tile[64][65];
  const int tid = threadIdx.x;
  const int tr = blockIdx.y * 64;
  const int tc = blockIdx.x * 64;
  const int lr = tid >> 4;
  const int lc = (tid & 15) * 4;
#pragma unroll
  for (int i = 0; i < 4; i++) {
    const float4 v = *(const float4*)(src + (size_t)(tr + lr + 16 * i) * C + tc + lc);
    tile[lr + 16 * i][lc + 0] = v.x;
    tile[lr + 16 * i][lc + 1] = v.y;
    tile[lr + 16 * i][lc + 2] = v.z;
    tile[lr + 16 * i][lc + 3] = v.w;
    store4bf(b + (size_t)(tr + lr + 16 * i) * C + tc + lc, f32x4{v.x, v.y, v.z, v.w});
  }
  __syncthreads();
#pragma unroll
  for (int j = 0; j < 16; j++) {
    const int idx = tid + j * 256;
    const int c = idx >> 6;
    const int rr = idx & 63;
    t[(size_t)(tc + c) * R + tr + rr] = f2bf(tile[rr][c]);
  }
}

__global__ void zero_k(unsigned int* p, int n) {
  const int i = blockIdx.x * blockDim.x + threadIdx.x;
  if (i < n) p[i] = 0u;
}

__global__ void initu_k(const float* __restrict__ u0, float* __restrict__ u,
                        unsigned short* __restrict__ ub, int n) {
  const int i = blockIdx.x * blockDim.x + threadIdx.x;
  if (i < n) {
    const float v = u0[i];
    u[i] = v;
    ub[i] = f2bf(v);
  }
}

__global__ __launch_bounds__(256) void r0_k(const float* __restrict__ inputs,
                                            unsigned short* __restrict__ r) {
  const int i = blockIdx.x * 256 + threadIdx.x;
  const f32x4 v = ((const f32x4*)inputs)[i];
  store4bf(r + (size_t)i * 4, f32x4{0.f, 0.f, 0.f, 0.f} - v);
}

extern "C" void kernel_launch(void* const* d_in, const int* in_sizes, int n_in,
                              void* d_out, int out_size, void* d_ws, size_t ws_size,
                              hipStream_t stream) {
  const float* inputs = (const float*)d_in[0];   // (BB, DD)
  const float* W      = (const float*)d_in[1];   // (KK, DD)
  const float* V      = (const float*)d_in[2];   // (CC, KK)
  const float* u0     = (const float*)d_in[3];   // (BB, CC)
  float* out = (float*)d_out;                    // (BB, DD)

  char* ws = (char*)d_ws;
  size_t off = 0;
  auto alloc = [&](size_t bytes) -> void* {
    void* p = ws + off;
    off += (bytes + 255) & ~(size_t)255;
    return p;
  };
  unsigned short* Wb = (unsigned short*)alloc((size_t)KK * DD * 2);  // W  (KK,DD)
  unsigned short* Wt = (unsigned short*)alloc((size_t)DD * KK * 2);  // W^T (DD,KK)
  unsigned short* Vb = (unsigned short*)alloc((size_t)CC * KK * 2);  // V  (CC,KK)
  unsigned short* Vt = (unsigned short*)alloc((size_t)KK * CC * 2);  // V^T (KK,CC)
  unsigned short* xb = (unsigned short*)alloc((size_t)BB * KK * 2);
  unsigned short* g  = (unsigned short*)alloc((size_t)BB * KK * 2);
  unsigned short* r  = (unsigned short*)alloc((size_t)BB * DD * 2);
  unsigned short* ub = (unsigned short*)alloc((size_t)BB * CC * 2);
  float* x = (float*)alloc((size_t)BB * KK * 4);
  float* u = (float*)alloc((size_t)BB * CC * 4);
  unsigned short* gxpb  = (unsigned short*)alloc((size_t)2 * BB * KK * 2);  // 8 MB
  unsigned short* zb    = (unsigned short*)alloc((size_t)BB * KK * 2);      // 4 MB
  unsigned short* outpb = (unsigned short*)alloc((size_t)4 * BB * DD * 2);  // 8 MB
  unsigned short* gupb  = (unsigned short*)alloc((size_t)8 * BB * CC * 2);  // 4 MB
  float* outp32 = (float*)alloc((size_t)4 * BB * DD * 4);                   // 16 MB

  convtrans_k<<<dim3(DD / 64, KK / 64), 256, 0, stream>>>(W, Wb, Wt, KK, DD);
  convtrans_k<<<dim3(KK / 64, CC / 64), 256, 0, stream>>>(V, Vb, Vt, CC, KK);
  zero_k<<<(BB * KK / 2 + 255) / 256, 256, 0, stream>>>((unsigned int*)xb, BB * KK / 2);
  zero_k<<<(BB * KK + 255) / 256, 256, 0, stream>>>((unsigned int*)x, BB * KK);
  initu_k<<<(BB * CC + 255) / 256, 256, 0, stream>>>(u0, u, ub, BB * CC);
  r0_k<<<BB * DD / 4 / 256, 256, 0, stream>>>(inputs, r);

  for (int t = 0; t < 9; t++) {
    // A: gx-partials_t (256 x 16 iters, bf16) + z_t (128 x 8 iters, bf16)
    zgxp_k<<<384, 256, 0, stream>>>(r, Wb, ub, Vt, gxpb, zb);
    // B: prox-x -> x_{t+1}, xb, g_t
    ep_x_k<<<BB * KK / 4 / 256, 256, 0, stream>>>(gxpb, zb, x, xb, g);
    if (t < 8) {
      // C: out_{t+1} (256 x 16, bf16) + gu_t (128 x 8, bf16)
      cgo_k<0><<<384, 256, 0, stream>>>(xb, Wt, g, Vb, outpb, gupb, nullptr);
      // D: u-prox_t (256 blocks) + r_{t+1} (1024 blocks)
      ud_k<<<1280, 256, 0, stream>>>(gupb, outpb, inputs, u, ub, r);
    } else {
      // C: out_9 partials fp32, then final sum -> d_out
      cgo_k<1><<<256, 256, 0, stream>>>(xb, Wt, g, Vb, outpb, gupb, outp32);
      ep_out_k<<<BB * DD / 4 / 256, 256, 0, stream>>>(outp32, out);
    }
  }
}